// Round 1
// baseline (275.700 us; speedup 1.0000x reference)
//
#include <hip/hip_runtime.h>

#define TOK 16384
#define DD 1024
#define OO 1024
#define KE 1056     // 1024 + 16 lora cols + 16 pad
#define NG 288      // 256 proj + 15 down + 17 pad
#define CLAMPV 4.605170185988091f

typedef __attribute__((ext_vector_type(8))) short short8;
typedef __attribute__((ext_vector_type(4))) float f32x4;

__device__ __forceinline__ unsigned short f2bf(float f) {
  unsigned int u = __float_as_uint(f);
  return (unsigned short)((u + 0x7FFFu + ((u >> 16) & 1u)) >> 16);
}

__device__ __forceinline__ void gload16(const unsigned short* g, unsigned short* l) {
  __builtin_amdgcn_global_load_lds(
      (const __attribute__((address_space(1))) void*)g,
      (__attribute__((address_space(3))) void*)l, 16, 0, 0);
}

// ---------------- kernel 0: prep (Wcat f32, Wb_ext bf16, x pad cols) ----------------
__global__ __launch_bounds__(256) void prep_kernel(
    const float* __restrict__ W, const float* __restrict__ Wp,
    const float* __restrict__ Wd0, const float* __restrict__ Wu0,
    const float* __restrict__ Wd1, const float* __restrict__ Wu1,
    const float* __restrict__ Wd2, const float* __restrict__ Wu2,
    const float* __restrict__ Wd3, const float* __restrict__ Wu3,
    float* __restrict__ Wcat, unsigned short* __restrict__ Bx,
    unsigned short* __restrict__ Ax) {
  const int nWcat = NG * DD;        // 294912
  const int nWb = OO * KE;          // 1081344
  const int nXpad = TOK * 16;       // 262144
  const int total = nWcat + nWb + nXpad;
  for (int i = blockIdx.x * 256 + threadIdx.x; i < total; i += gridDim.x * 256) {
    if (i < nWcat) {
      int row = i >> 10, c = i & 1023;
      float v = 0.f;
      if (row < 256) v = Wp[row * DD + c];
      else if (row == 256) v = Wd0[c];
      else if (row < 259) v = Wd1[(row - 257) * DD + c];
      else if (row < 263) v = Wd2[(row - 259) * DD + c];
      else if (row < 271) v = Wd3[(row - 263) * DD + c];
      Wcat[i] = v;
    } else if (i < nWcat + nWb) {
      int j = i - nWcat;
      int o = j / KE, c = j - o * KE;
      float v = 0.f;
      if (c < 1024) v = W[o * DD + c];
      else if (c == 1024) v = Wu0[o];
      else if (c < 1027) v = Wu1[o * 2 + (c - 1025)];
      else if (c < 1031) v = Wu2[o * 4 + (c - 1027)];
      else if (c < 1039) v = Wu3[o * 8 + (c - 1031)];
      Bx[j] = f2bf(v);
    } else {
      int j = i - nWcat - nWb;
      int row = j >> 4, c = j & 15;
      Ax[row * KE + 1040 + c] = 0;
    }
  }
}

// ---------------- kernel 1: fp32 gate GEMM [16384,1024]x[288,1024]^T + x->bf16 ----------------
// 256 threads: tr=tid>>4 (rows 4tr..4tr+3), tc=tid&15 (cols 16tc..16tc+15 and 256+2tc..+1)
__global__ __launch_bounds__(256) void gate_gemm(
    const float* __restrict__ x, const float* __restrict__ Wcat,
    const float* __restrict__ bp, float* __restrict__ Cg,
    unsigned short* __restrict__ Ax) {
  __shared__ __align__(16) float xs[32 * 68];    // [k][row], stride 68
  __shared__ __align__(16) float wsA[16 * 516];  // [group g][k*16 + j], stride 516
  __shared__ __align__(16) float wsB[32 * 34];   // [k][down col], stride 34
  const int tid = threadIdx.x;
  const int tr = tid >> 4, tc = tid & 15;
  const int rowBase = blockIdx.x * 64;
  float acc[4][16];
  float acc2[4][2];
#pragma unroll
  for (int i = 0; i < 4; ++i) {
#pragma unroll
    for (int j = 0; j < 16; ++j) acc[i][j] = 0.f;
    acc2[i][0] = 0.f; acc2[i][1] = 0.f;
  }
  const int xr = tid >> 2;          // 0..63
  const int xc = (tid & 3) * 8;     // 0,8,16,24
  for (int kt = 0; kt < 32; ++kt) {
    // stage x tile [64][32] (transposed into xs) + emit bf16 copy
    {
      const float* gp = &x[(rowBase + xr) * DD + kt * 32 + xc];
      float4 v0 = *(const float4*)gp;
      float4 v1 = *(const float4*)(gp + 4);
      float vv[8] = {v0.x, v0.y, v0.z, v0.w, v1.x, v1.y, v1.z, v1.w};
#pragma unroll
      for (int t = 0; t < 8; ++t) xs[(xc + t) * 68 + xr] = vv[t];
      union { unsigned short s[8]; int4 q; } pk;
#pragma unroll
      for (int t = 0; t < 8; ++t) pk.s[t] = f2bf(vv[t]);
      *reinterpret_cast<int4*>(&Ax[(rowBase + xr) * KE + kt * 32 + xc]) = pk.q;
    }
    // stage Wcat tile [288][32] transposed: 2304 float4 loads / 256 threads = 9
#pragma unroll
    for (int it = 0; it < 9; ++it) {
      int idx = tid + it * 256;
      int col = idx >> 3;
      int cc = (idx & 7) * 4;
      float4 v = *(const float4*)&Wcat[col * DD + kt * 32 + cc];
      if (col < 256) {
        float* b2 = &wsA[(col >> 4) * 516 + (col & 15)];
        b2[(cc + 0) * 16] = v.x;
        b2[(cc + 1) * 16] = v.y;
        b2[(cc + 2) * 16] = v.z;
        b2[(cc + 3) * 16] = v.w;
      } else {
        int j = col - 256;
        wsB[(cc + 0) * 34 + j] = v.x;
        wsB[(cc + 1) * 34 + j] = v.y;
        wsB[(cc + 2) * 34 + j] = v.z;
        wsB[(cc + 3) * 34 + j] = v.w;
      }
    }
    __syncthreads();
#pragma unroll 4
    for (int k = 0; k < 32; ++k) {
      float4 xv = *(const float4*)&xs[k * 68 + tr * 4];
      const float* wp2 = &wsA[tc * 516 + k * 16];
      float4 w0 = *(const float4*)(wp2);
      float4 w1 = *(const float4*)(wp2 + 4);
      float4 w2 = *(const float4*)(wp2 + 8);
      float4 w3 = *(const float4*)(wp2 + 12);
      float2 wb2 = *(const float2*)&wsB[k * 34 + tc * 2];
      float xa[4] = {xv.x, xv.y, xv.z, xv.w};
      float wa[16] = {w0.x, w0.y, w0.z, w0.w, w1.x, w1.y, w1.z, w1.w,
                      w2.x, w2.y, w2.z, w2.w, w3.x, w3.y, w3.z, w3.w};
#pragma unroll
      for (int i = 0; i < 4; ++i) {
#pragma unroll
        for (int j = 0; j < 16; ++j) acc[i][j] = __builtin_fmaf(xa[i], wa[j], acc[i][j]);
        acc2[i][0] = __builtin_fmaf(xa[i], wb2.x, acc2[i][0]);
        acc2[i][1] = __builtin_fmaf(xa[i], wb2.y, acc2[i][1]);
      }
    }
    __syncthreads();
  }
#pragma unroll
  for (int i = 0; i < 4; ++i) {
    float* outp = &Cg[(rowBase + tr * 4 + i) * NG];
#pragma unroll
    for (int q = 0; q < 4; ++q) {
      float4 vv;
      vv.x = acc[i][q * 4 + 0] + bp[tc * 16 + q * 4 + 0];
      vv.y = acc[i][q * 4 + 1] + bp[tc * 16 + q * 4 + 1];
      vv.z = acc[i][q * 4 + 2] + bp[tc * 16 + q * 4 + 2];
      vv.w = acc[i][q * 4 + 3] + bp[tc * 16 + q * 4 + 3];
      *reinterpret_cast<float4*>(&outp[tc * 16 + q * 4]) = vv;
    }
    float2 v2; v2.x = acc2[i][0]; v2.y = acc2[i][1];
    *reinterpret_cast<float2*>(&outp[256 + tc * 2]) = v2;
  }
}

// ---------------- kernel 2: gate finalize (norms, logits, softmax, top1, sdown16) ----------------
__global__ __launch_bounds__(256) void gate_finalize(
    const float* __restrict__ Cg, const float* __restrict__ sim,
    const float* __restrict__ temp, unsigned short* __restrict__ Ax) {
  const int tid = threadIdx.x;
  const int lane = tid & 63, wv = tid >> 6;
  const int n = blockIdx.x * 4 + wv;
  const float* row = &Cg[n * NG];
  float4 p = *(const float4*)&row[lane * 4];
  const float4* sp = (const float4*)&sim[lane * 16];  // sim rows 4l..4l+3, [256][4]
  float4 s0 = sp[0], s1 = sp[1], s2 = sp[2], s3 = sp[3];
  float red[9];
  red[0] = p.x * p.x + p.y * p.y + p.z * p.z + p.w * p.w;           // ||proj||^2
  red[1] = p.x * s0.x + p.y * s1.x + p.z * s2.x + p.w * s3.x;       // dot e=0
  red[2] = p.x * s0.y + p.y * s1.y + p.z * s2.y + p.w * s3.y;
  red[3] = p.x * s0.z + p.y * s1.z + p.z * s2.z + p.w * s3.z;
  red[4] = p.x * s0.w + p.y * s1.w + p.z * s2.w + p.w * s3.w;
  red[5] = s0.x * s0.x + s1.x * s1.x + s2.x * s2.x + s3.x * s3.x;   // ||sim_e||^2
  red[6] = s0.y * s0.y + s1.y * s1.y + s2.y * s2.y + s3.y * s3.y;
  red[7] = s0.z * s0.z + s1.z * s1.z + s2.z * s2.z + s3.z * s3.z;
  red[8] = s0.w * s0.w + s1.w * s1.w + s2.w * s2.w + s3.w * s3.w;
#pragma unroll
  for (int off = 32; off; off >>= 1) {
#pragma unroll
    for (int t = 0; t < 9; ++t) red[t] += __shfl_xor(red[t], off, 64);
  }
  float norm = fmaxf(sqrtf(red[0]), 1e-12f);
  float scale = expf(fminf(temp[0], CLAMPV));
  float l[4];
#pragma unroll
  for (int e = 0; e < 4; ++e) {
    float sn = fmaxf(sqrtf(red[5 + e]), 1e-12f);
    l[e] = scale * red[1 + e] / (norm * sn);
  }
  int be = 0; float best = l[0];
  if (l[1] > best) { best = l[1]; be = 1; }
  if (l[2] > best) { best = l[2]; be = 2; }
  if (l[3] > best) { best = l[3]; be = 3; }
  float denom = expf(l[0] - best) + expf(l[1] - best) + expf(l[2] - best) + expf(l[3] - best);
  float g = 1.0f / denom;   // softmax prob of the argmax entry
  const int offA[4] = {0, 1, 3, 7};
  const int rrA[4] = {1, 2, 4, 8};
  if (lane < 16) {
    int j = lane;
    float v = 0.f;
    if (j >= offA[be] && j < offA[be] + rrA[be]) v = g * row[256 + j];
    Ax[n * KE + 1024 + j] = f2bf(v);
  }
}

// ---------------- kernel 3: bf16 MFMA GEMM C[16384,1024] = A[16384,1056] @ B[1024,1056]^T ----------------
__global__ __launch_bounds__(256) void main_gemm(
    const unsigned short* __restrict__ A, const unsigned short* __restrict__ Bm,
    float* __restrict__ C) {
  __shared__ __align__(16) unsigned short as_[2][128 * 32];
  __shared__ __align__(16) unsigned short bs_[2][128 * 32];
  const int tid = threadIdx.x;
  const int lane = tid & 63, wv = tid >> 6;
  const int wm = wv >> 1, wn = wv & 1;
  const int r0 = blockIdx.y * 128, c0 = blockIdx.x * 128;
  f32x4 acc[4][4] = {};
  const int se = wv * 512 + lane * 8;        // elem offset in 2048-elem (64-row) chunk
  const int sr = se >> 5, sc = se & 31;
  const unsigned short* ga0 = &A[(r0 + sr) * KE + sc];
  const unsigned short* gb0 = &Bm[(c0 + sr) * KE + sc];
  // prologue: stage kt=0 into buf 0
  gload16(ga0, &as_[0][wv * 512]);
  gload16(ga0 + 64 * KE, &as_[0][2048 + wv * 512]);
  gload16(gb0, &bs_[0][wv * 512]);
  gload16(gb0 + 64 * KE, &bs_[0][2048 + wv * 512]);
  const int ro = lane & 15, ko = (lane >> 4) * 8;
  int cur = 0;
  for (int kt = 0; kt < 33; ++kt) {
    __syncthreads();
    if (kt + 1 < 33) {
      const unsigned short* ga = ga0 + (kt + 1) * 32;
      const unsigned short* gb = gb0 + (kt + 1) * 32;
      int nb = cur ^ 1;
      gload16(ga, &as_[nb][wv * 512]);
      gload16(ga + 64 * KE, &as_[nb][2048 + wv * 512]);
      gload16(gb, &bs_[nb][wv * 512]);
      gload16(gb + 64 * KE, &bs_[nb][2048 + wv * 512]);
    }
    const unsigned short* ap = &as_[cur][0];
    const unsigned short* bpp = &bs_[cur][0];
    short8 af[4], bf[4];
#pragma unroll
    for (int m = 0; m < 4; ++m)
      af[m] = *reinterpret_cast<const short8*>(ap + (wm * 64 + m * 16 + ro) * 32 + ko);
#pragma unroll
    for (int n = 0; n < 4; ++n)
      bf[n] = *reinterpret_cast<const short8*>(bpp + (wn * 64 + n * 16 + ro) * 32 + ko);
#pragma unroll
    for (int m = 0; m < 4; ++m)
#pragma unroll
      for (int n = 0; n < 4; ++n)
        acc[m][n] = __builtin_amdgcn_mfma_f32_16x16x32_bf16(af[m], bf[n], acc[m][n], 0, 0, 0);
    cur ^= 1;
  }
#pragma unroll
  for (int m = 0; m < 4; ++m) {
    int rr = r0 + wm * 64 + m * 16 + (lane >> 4) * 4;
#pragma unroll
    for (int n = 0; n < 4; ++n) {
      int cc = c0 + wn * 64 + n * 16 + (lane & 15);
#pragma unroll
      for (int v = 0; v < 4; ++v)
        C[(rr + v) * OO + cc] = acc[m][n][v];
    }
  }
}

extern "C" void kernel_launch(void* const* d_in, const int* in_sizes, int n_in,
                              void* d_out, int out_size, void* d_ws, size_t ws_size,
                              hipStream_t stream) {
  const float* x    = (const float*)d_in[0];
  const float* W    = (const float*)d_in[1];
  const float* Wp   = (const float*)d_in[2];
  const float* bp   = (const float*)d_in[3];
  const float* sim  = (const float*)d_in[4];
  const float* temp = (const float*)d_in[5];
  const float* Wd0  = (const float*)d_in[6];
  const float* Wu0  = (const float*)d_in[7];
  const float* Wd1  = (const float*)d_in[8];
  const float* Wu1  = (const float*)d_in[9];
  const float* Wd2  = (const float*)d_in[10];
  const float* Wu2  = (const float*)d_in[11];
  const float* Wd3  = (const float*)d_in[12];
  const float* Wu3  = (const float*)d_in[13];
  float* out = (float*)d_out;
  char* ws = (char*)d_ws;
  // ws layout (total 56,819,712 B):
  float* Cg = (float*)ws;                                             // [16384][288] f32
  unsigned short* Ax = (unsigned short*)(ws + 18874368);              // [16384][1056] bf16
  unsigned short* Bx = (unsigned short*)(ws + 18874368 + 34603008);   // [1024][1056] bf16
  float* Wcat = (float*)(ws + 18874368 + 34603008 + 2162688);         // [288][1024] f32

  prep_kernel<<<1024, 256, 0, stream>>>(W, Wp, Wd0, Wu0, Wd1, Wu1, Wd2, Wu2, Wd3, Wu3,
                                        Wcat, Bx, Ax);
  gate_gemm<<<256, 256, 0, stream>>>(x, Wcat, bp, Cg, Ax);
  gate_finalize<<<4096, 256, 0, stream>>>(Cg, sim, temp, Ax);
  main_gemm<<<dim3(8, 128), 256, 0, stream>>>(Ax, Bx, out);
}